// Round 1
// baseline (197.226 us; speedup 1.0000x reference)
//
#include <hip/hip_runtime.h>

#define TH 16
#define TW 64
#define HALO 5
#define SM_H (TH + 2*HALO)      // 26
#define SM_W (TW + 2*HALO)      // 74
#define SM_STRIDE (SM_W + 2)    // 76
#define DM_H (TH + 2)           // 18
#define DM_W (TW + 2)           // 66
#define DM_STRIDE (DM_W + 2)    // 68

__global__ __launch_bounds__(256) void demosaick_kernel(
    const float* __restrict__ mosaick,
    const float* __restrict__ gfilt,
    const float* __restrict__ gradfilt,
    float* __restrict__ out,
    int B, int H, int W)
{
    __shared__ float sm[SM_H][SM_STRIDE];
    __shared__ float dm[DM_H][DM_STRIDE];

    const int tid = threadIdx.x;
    const int bx = blockIdx.x;        // W / TW tiles
    const int by = blockIdx.y;        // H / TH tiles
    const int b  = blockIdx.z;

    const int x0 = bx * TW;
    const int y0 = by * TH;

    const float* img = mosaick + (size_t)b * H * W;

    // Filters (uniform loads, L2-cached broadcast)
    float gf[9], df[9];
    #pragma unroll
    for (int i = 0; i < 9; ++i) { gf[i] = gfilt[i]; df[i] = gradfilt[i]; }

    // ---- Stage mosaick tile with clamped (edge-replicate) halo of 5 ----
    for (int i = tid; i < SM_H * SM_W; i += 256) {
        int ly = i / SM_W, lx = i - ly * SM_W;
        int gy = y0 + ly - HALO; gy = min(max(gy, 0), H - 1);
        int gx = x0 + lx - HALO; gx = min(max(gx, 0), W - 1);
        sm[ly][lx] = img[(size_t)gy * W + gx];
    }
    __syncthreads();

    // ---- Compute d = mosaick - green on (TH+2)x(TW+2), zero outside image ----
    for (int i = tid; i < DM_H * DM_W; i += 256) {
        int ly = i / DM_W, lx = i - ly * DM_W;
        int sy = ly + (HALO - 1), sx = lx + (HALO - 1);
        int gy = y0 + ly - 1, gx = x0 + lx - 1;
        float m = sm[sy][sx];
        float ih = 0.f, iv = 0.f, dxv = 0.f, dyv = 0.f;
        #pragma unroll
        for (int r = 0; r < 9; ++r) {
            float hx = sm[sy][sx + r - 4];
            float vx = sm[sy + r - 4][sx];
            ih  += gf[r] * hx;  iv  += gf[r] * vx;
            dxv += df[r] * hx;  dyv += df[r] * vx;
        }
        float adx = fabsf(dxv), ady = fabsf(dyv);
        float wh = ady / (adx + ady + 1e-5f);
        float gi = wh * ih + (1.f - wh) * iv;
        bool gsite = (((gx + gy) & 1) == 0);
        float green = gsite ? m : gi;
        bool valid = (gy >= 0) && (gy < H) && (gx >= 0) && (gx < W);
        dm[ly][lx] = valid ? (m - green) : 0.f;
    }
    __syncthreads();

    // ---- Chroma 3x3 (zero-padded) + output ----
    const float kbw[9] = {0.25f, 0.5f, 0.25f,
                          0.5f,  1.0f, 0.5f,
                          0.25f, 0.5f, 0.25f};
    const size_t plane = (size_t)H * W;
    float* outb = out + (size_t)b * 3 * plane;
    const int tx  = tid & 63;
    const int ty0 = tid >> 6;

    #pragma unroll
    for (int k = 0; k < 4; ++k) {
        int ty = ty0 * 4 + k;
        int gy = y0 + ty, gx = x0 + tx;
        float green = sm[ty + HALO][tx + HALO] - dm[ty + 1][tx + 1];
        float cr = 0.f, cb = 0.f;
        #pragma unroll
        for (int di = -1; di <= 1; ++di) {
            #pragma unroll
            for (int dj = -1; dj <= 1; ++dj) {
                float w = kbw[(di + 1) * 3 + (dj + 1)];
                float d = dm[ty + 1 + di][tx + 1 + dj];
                int ny = gy + di, nx = gx + dj;
                bool isr = ((ny & 1) == 0) && ((nx & 1) == 1);
                bool isb = ((ny & 1) == 1) && ((nx & 1) == 0);
                cr += isr ? w * d : 0.f;
                cb += isb ? w * d : 0.f;
            }
        }
        size_t o = (size_t)gy * W + gx;
        outb[o]             = green + cr;
        outb[plane + o]     = green;
        outb[2 * plane + o] = green + cb;
    }
}

extern "C" void kernel_launch(void* const* d_in, const int* in_sizes, int n_in,
                              void* d_out, int out_size, void* d_ws, size_t ws_size,
                              hipStream_t stream) {
    const float* mosaick  = (const float*)d_in[0];
    const float* gfilt    = (const float*)d_in[1];
    const float* gradfilt = (const float*)d_in[2];
    float* out = (float*)d_out;

    const int H = 1024, W = 1024;
    const int B = in_sizes[0] / (H * W);

    dim3 grid(W / TW, H / TH, B);
    demosaick_kernel<<<grid, 256, 0, stream>>>(mosaick, gfilt, gradfilt, out, B, H, W);
}

// Round 2
// 154.890 us; speedup vs baseline: 1.2733x; 1.2733x over previous
//
#include <hip/hip_runtime.h>

#define TH 32
#define TW 128
#define HY 5
#define HX 8
#define SM_H (TH + 2*HY)      // 42
#define SM_W (TW + 2*HX)      // 144 floats (16B-aligned rows)
#define DM_H (TH + 2)         // 34
#define DM_W (TW + 8)         // 136: dm x range [-4, 131]

__device__ __forceinline__ float f4get(const float4& v, int j) {
    return ((const float*)&v)[j];
}

__global__ __launch_bounds__(256) void demosaick_kernel(
    const float* __restrict__ mosaick,
    const float* __restrict__ gfilt,
    const float* __restrict__ gradfilt,
    float* __restrict__ out,
    int B, int H, int W)
{
    __shared__ float sm[SM_H][SM_W];
    __shared__ float dm[DM_H][DM_W];

    const int tid = threadIdx.x;
    const int x0 = blockIdx.x * TW;
    const int y0 = blockIdx.y * TH;
    const int b  = blockIdx.z;

    const float* img = mosaick + (size_t)b * H * W;

    float gf[9], df[9];
    #pragma unroll
    for (int i = 0; i < 9; ++i) { gf[i] = gfilt[i]; df[i] = gradfilt[i]; }

    // ---- Stage mosaick tile (float4), edge-replicate clamp ----
    const int NS4 = SM_H * (SM_W / 4);          // 42*36 = 1512
    for (int i = tid; i < NS4; i += 256) {
        int ly = i / (SM_W / 4);
        int lx4 = (i - ly * (SM_W / 4)) * 4;
        int gy = y0 + ly - HY; gy = min(max(gy, 0), H - 1);
        int gx = x0 + lx4 - HX;
        const float* row = img + (size_t)gy * W;
        float4 v;
        if (gx >= 0 && gx + 3 < W) {
            v = *reinterpret_cast<const float4*>(row + gx);
        } else {
            int g0 = min(max(gx,     0), W - 1);
            int g1 = min(max(gx + 1, 0), W - 1);
            int g2 = min(max(gx + 2, 0), W - 1);
            int g3 = min(max(gx + 3, 0), W - 1);
            v = make_float4(row[g0], row[g1], row[g2], row[g3]);
        }
        *reinterpret_cast<float4*>(&sm[ly][lx4]) = v;
    }
    __syncthreads();

    // ---- d = mosaick - green on [-1..32] x [-4..131], zero outside image ----
    const int ND4 = DM_H * (DM_W / 4);          // 34*34 = 1156
    for (int i = tid; i < ND4; i += 256) {
        int ly = i / (DM_W / 4);
        int lx4 = (i - ly * (DM_W / 4)) * 4;
        int sy = ly + (HY - 1);                 // dm y=-1 -> sm row 4
        int sx = lx4 + (HX - 4);                // dm x=-4 -> sm col 4
        int gy = y0 + ly - 1;
        int gx0 = x0 + lx4 - 4;

        float4 vv[9];
        #pragma unroll
        for (int r = 0; r < 9; ++r)
            vv[r] = *reinterpret_cast<const float4*>(&sm[sy + r - 4][sx]);
        float h[12];
        *reinterpret_cast<float4*>(&h[0]) = *reinterpret_cast<const float4*>(&sm[sy][sx - 4]);
        *reinterpret_cast<float4*>(&h[4]) = vv[4];
        *reinterpret_cast<float4*>(&h[8]) = *reinterpret_cast<const float4*>(&sm[sy][sx + 4]);

        float4 dres;
        #pragma unroll
        for (int j = 0; j < 4; ++j) {
            float ih = 0.f, iv = 0.f, dxv = 0.f, dyv = 0.f;
            #pragma unroll
            for (int r = 0; r < 9; ++r) {
                float hx = h[j + r];
                float vx = f4get(vv[r], j);
                ih  += gf[r] * hx;  dxv += df[r] * hx;
                iv  += gf[r] * vx;  dyv += df[r] * vx;
            }
            float adx = fabsf(dxv), ady = fabsf(dyv);
            float wh = ady * __builtin_amdgcn_rcpf(adx + ady + 1e-5f);
            float gi = wh * ih + (1.f - wh) * iv;
            float m  = f4get(vv[4], j);
            int gx = gx0 + j;
            bool gsite = (((gx + gy) & 1) == 0);
            float dv = gsite ? 0.f : (m - gi);
            bool valid = (gy >= 0) & (gy < H) & (gx >= 0) & (gx < W);
            ((float*)&dres)[j] = valid ? dv : 0.f;
        }
        *reinterpret_cast<float4*>(&dm[ly][lx4]) = dres;
    }
    __syncthreads();

    // ---- Chroma (parity-separated 3x3) + vectorized stores ----
    const size_t plane = (size_t)H * W;
    float* outb = out + (size_t)b * 3 * plane;
    const int tx4 = (tid & 31) * 4;
    const int ty0 = tid >> 5;

    #pragma unroll
    for (int k = 0; k < 4; ++k) {
        int ty = ty0 + 8 * k;
        int gy = y0 + ty;
        int ly = ty + 1;
        int c  = tx4 + 4;                       // dm col of pixel j=0

        float4 m4 = *reinterpret_cast<const float4*>(&sm[ty + HY][tx4 + HX]);
        float ra[12], rb[12], rc[12];
        *reinterpret_cast<float4*>(&ra[0]) = *reinterpret_cast<const float4*>(&dm[ly - 1][c - 4]);
        *reinterpret_cast<float4*>(&ra[4]) = *reinterpret_cast<const float4*>(&dm[ly - 1][c]);
        *reinterpret_cast<float4*>(&ra[8]) = *reinterpret_cast<const float4*>(&dm[ly - 1][c + 4]);
        *reinterpret_cast<float4*>(&rb[0]) = *reinterpret_cast<const float4*>(&dm[ly][c - 4]);
        *reinterpret_cast<float4*>(&rb[4]) = *reinterpret_cast<const float4*>(&dm[ly][c]);
        *reinterpret_cast<float4*>(&rb[8]) = *reinterpret_cast<const float4*>(&dm[ly][c + 4]);
        *reinterpret_cast<float4*>(&rc[0]) = *reinterpret_cast<const float4*>(&dm[ly + 1][c - 4]);
        *reinterpret_cast<float4*>(&rc[4]) = *reinterpret_cast<const float4*>(&dm[ly + 1][c]);
        *reinterpret_cast<float4*>(&rc[8]) = *reinterpret_cast<const float4*>(&dm[ly + 1][c + 4]);

        int p = gy & 1;
        float4 R4, G4, B4;
        #pragma unroll
        for (int j = 0; j < 4; ++j) {
            float d00  = rb[j + 4];
            float S_ee = d00;
            float S_eo = 0.5f  * (rb[j + 3] + rb[j + 5]);
            float S_oe = 0.5f  * (ra[j + 4] + rc[j + 4]);
            float S_oo = 0.25f * (ra[j + 3] + ra[j + 5] + rc[j + 3] + rc[j + 5]);
            float cr, cb;
            if ((j & 1) == 0) {                 // x even
                cr = p ? S_oo : S_eo;
                cb = p ? S_ee : S_oe;
            } else {                            // x odd
                cr = p ? S_oe : S_ee;
                cb = p ? S_eo : S_oo;
            }
            float green = f4get(m4, j) - d00;
            ((float*)&R4)[j] = green + cr;
            ((float*)&G4)[j] = green;
            ((float*)&B4)[j] = green + cb;
        }
        size_t o = (size_t)gy * W + (x0 + tx4);
        *reinterpret_cast<float4*>(&outb[o])             = R4;
        *reinterpret_cast<float4*>(&outb[plane + o])     = G4;
        *reinterpret_cast<float4*>(&outb[2 * plane + o]) = B4;
    }
}

extern "C" void kernel_launch(void* const* d_in, const int* in_sizes, int n_in,
                              void* d_out, int out_size, void* d_ws, size_t ws_size,
                              hipStream_t stream) {
    const float* mosaick  = (const float*)d_in[0];
    const float* gfilt    = (const float*)d_in[1];
    const float* gradfilt = (const float*)d_in[2];
    float* out = (float*)d_out;

    const int H = 1024, W = 1024;
    const int B = in_sizes[0] / (H * W);

    dim3 grid(W / TW, H / TH, B);
    demosaick_kernel<<<grid, 256, 0, stream>>>(mosaick, gfilt, gradfilt, out, B, H, W);
}

// Round 3
// 120.445 us; speedup vs baseline: 1.6375x; 1.2860x over previous
//
#include <hip/hip_runtime.h>

constexpr int IW = 1024;
constexpr int IH = 1024;
constexpr int BH = 32;

__device__ __forceinline__ float4 splat4(float v){ return make_float4(v,v,v,v); }

__global__ __launch_bounds__(256) void demosaick_kernel(
    const float* __restrict__ mosaick,
    const float* __restrict__ gfilt,
    const float* __restrict__ gradfilt,
    float* __restrict__ out)
{
    __shared__ float4 mbuf[258];   // slot tid+1 = lane's m float4 of exchange row
    __shared__ float  dlbuf[257];  // dl[tid+1] = lane's d.w ; dl[0] = 0 (image left edge)
    __shared__ float  drbuf[257];  // dr[tid]   = lane's d.x ; dr[256] = 0 (image right edge)

    const int tid = threadIdx.x;
    const int y0  = blockIdx.x * BH;
    const int b   = blockIdx.y;
    const int x0  = tid * 4;

    const float* img = mosaick + (size_t)b * IH * IW;

    float gf[9], df[9];
    #pragma unroll
    for (int i = 0; i < 9; ++i) { gf[i] = gfilt[i]; df[i] = gradfilt[i]; }

    // m[k] holds row (rd-4+k) when computing d-row rd (center = m[4])
    float4 m[9];
    #pragma unroll
    for (int k = 0; k < 9; ++k) {
        int ry = min(max(y0 - 5 + k, 0), IH - 1);
        m[k] = *reinterpret_cast<const float4*>(img + (size_t)ry * IW + x0);
    }
    if (tid == 0) { dlbuf[0] = 0.f; drbuf[256] = 0.f; }

    // compute d-row rd from current m[] (center m[4]) + horizontal halo hL/hR
    auto computeD = [&](const float4 hL, const float4 hR, int rd) -> float4 {
        float h[12];
        h[0]=hL.x; h[1]=hL.y; h[2]=hL.z; h[3]=hL.w;
        h[4]=m[4].x; h[5]=m[4].y; h[6]=m[4].z; h[7]=m[4].w;
        h[8]=hR.x; h[9]=hR.y; h[10]=hR.z; h[11]=hR.w;
        bool vr = ((unsigned)rd) < (unsigned)IH;
        float4 dres;
        #pragma unroll
        for (int j = 0; j < 4; ++j) {
            float ih = 0.f, dx = 0.f, iv = 0.f, dy = 0.f;
            #pragma unroll
            for (int k = 0; k < 9; ++k) {
                ih = fmaf(gf[k], h[j + k], ih);
                dx = fmaf(df[k], h[j + k], dx);
            }
            #pragma unroll
            for (int k = 0; k < 9; ++k) {
                float mv = ((const float*)&m[k])[j];
                iv = fmaf(gf[k], mv, iv);
                dy = fmaf(df[k], mv, dy);
            }
            float adx = fabsf(dx), ady = fabsf(dy);
            float wh = ady * __builtin_amdgcn_rcpf(adx + ady + 1e-5f);
            float gi = fmaf(wh, ih - iv, iv);
            float mc = ((const float*)&m[4])[j];
            int gx = x0 + j;
            bool gsite = (((gx + rd) & 1) == 0);
            float dv = (gsite || !vr) ? 0.f : (mc - gi);
            ((float*)&dres)[j] = dv;
        }
        return dres;
    };

    float4 dA, dB;               // d rows r-1, r
    float  dlA, drA, dlB, drB;

    // ---- warmup A: d row y0-1 (m[0..8] = rows y0-5..y0+3, center m[4]=y0-1) ----
    mbuf[tid + 1] = m[4];
    __syncthreads();
    {
        float4 hL = (tid == 0)   ? splat4(m[4].x) : mbuf[tid];
        float4 hR = (tid == 255) ? splat4(m[4].w) : mbuf[tid + 2];
        float4 d0 = computeD(hL, hR, y0 - 1);
        dlbuf[tid + 1] = d0.w; drbuf[tid] = d0.x;
        __syncthreads();
        dA = d0; dlA = dlbuf[tid]; drA = drbuf[tid + 1];
    }
    // ---- warmup B: d row y0 ----
    {
        int ry = min(y0 + 4, IH - 1);
        float4 mNew = *reinterpret_cast<const float4*>(img + (size_t)ry * IW + x0);
        mbuf[tid + 1] = m[5];
        __syncthreads();
        float4 hL = (tid == 0)   ? splat4(m[5].x) : mbuf[tid];
        float4 hR = (tid == 255) ? splat4(m[5].w) : mbuf[tid + 2];
        #pragma unroll
        for (int k = 0; k < 8; ++k) m[k] = m[k + 1];
        m[8] = mNew;
        float4 d0 = computeD(hL, hR, y0);
        dlbuf[tid + 1] = d0.w; drbuf[tid] = d0.x;
        __syncthreads();
        dB = d0; dlB = dlbuf[tid]; drB = drbuf[tid + 1];
    }

    const size_t plane = (size_t)IH * IW;
    float* outb = out + (size_t)b * 3 * plane;

    for (int r = y0; r < y0 + BH; ++r) {
        int ry = min(r + 5, IH - 1);
        float4 mNew = *reinterpret_cast<const float4*>(img + (size_t)ry * IW + x0);

        // exchange horizontal halo of m row r+1 (= m[5] pre-shift)
        mbuf[tid + 1] = m[5];
        __syncthreads();
        float4 hL = (tid == 0)   ? splat4(m[5].x) : mbuf[tid];
        float4 hR = (tid == 255) ? splat4(m[5].w) : mbuf[tid + 2];

        #pragma unroll
        for (int k = 0; k < 8; ++k) m[k] = m[k + 1];
        m[8] = mNew;

        float4 dC = computeD(hL, hR, r + 1);
        dlbuf[tid + 1] = dC.w; drbuf[tid] = dC.x;
        __syncthreads();
        float dlC = dlbuf[tid], drC = drbuf[tid + 1];

        // ---- chroma + output at row r (m row r = m[3]) ----
        float A6[6] = { dlA, dA.x, dA.y, dA.z, dA.w, drA };
        float B6[6] = { dlB, dB.x, dB.y, dB.z, dB.w, drB };
        float C6[6] = { dlC, dC.x, dC.y, dC.z, dC.w, drC };
        int p = r & 1;
        float4 R4, G4, B4;
        #pragma unroll
        for (int j = 0; j < 4; ++j) {
            float d00  = B6[j + 1];
            float S_ee = d00;
            float S_eo = 0.5f  * (B6[j] + B6[j + 2]);
            float S_oe = 0.5f  * (A6[j + 1] + C6[j + 1]);
            float S_oo = 0.25f * (A6[j] + A6[j + 2] + C6[j] + C6[j + 2]);
            float cr, cb;
            if ((j & 1) == 0) { cr = p ? S_oo : S_eo; cb = p ? S_ee : S_oe; }
            else              { cr = p ? S_oe : S_ee; cb = p ? S_eo : S_oo; }
            float green = ((const float*)&m[3])[j] - d00;
            ((float*)&R4)[j] = green + cr;
            ((float*)&G4)[j] = green;
            ((float*)&B4)[j] = green + cb;
        }
        size_t o = (size_t)r * IW + x0;
        *reinterpret_cast<float4*>(outb + o)             = R4;
        *reinterpret_cast<float4*>(outb + plane + o)     = G4;
        *reinterpret_cast<float4*>(outb + 2 * plane + o) = B4;

        dA = dB; dlA = dlB; drA = drB;
        dB = dC; dlB = dlC; drB = drC;
    }
}

extern "C" void kernel_launch(void* const* d_in, const int* in_sizes, int n_in,
                              void* d_out, int out_size, void* d_ws, size_t ws_size,
                              hipStream_t stream) {
    const float* mosaick  = (const float*)d_in[0];
    const float* gfilt    = (const float*)d_in[1];
    const float* gradfilt = (const float*)d_in[2];
    float* out = (float*)d_out;

    const int B = in_sizes[0] / (IH * IW);
    dim3 grid(IH / BH, B);
    demosaick_kernel<<<grid, 256, 0, stream>>>(mosaick, gfilt, gradfilt, out);
}